// Round 1
// baseline (207.580 us; speedup 1.0000x reference)
//
#include <hip/hip_runtime.h>
#include <hip/hip_bf16.h>
#include <stdint.h>

#define M_ROWS 8192
#define K_IN   2048
#define N_OUT  2048

typedef __bf16 bf16x8 __attribute__((ext_vector_type(8)));
typedef float  f32x4  __attribute__((ext_vector_type(4)));

// ---------------------------------------------------------------------------
// async global->LDS, 16B per lane. LDS dest must be wave-uniform base + lane*16.
__device__ __forceinline__ void load_lds16(const void* g, void* l) {
    __builtin_amdgcn_global_load_lds(
        (const __attribute__((address_space(1))) uint32_t*)g,
        (__attribute__((address_space(3))) uint32_t*)l,
        16, 0, 0);
}

__device__ __forceinline__ uint16_t f32_to_bf16_bits(float f) {
    union { float f; uint32_t u; } c; c.f = f;
    uint32_t r = c.u + 0x7FFFu + ((c.u >> 16) & 1u);  // RNE
    return (uint16_t)(r >> 16);
}

// ---------------------------------------------------------------------------
// Kernel 1: per-row absmax scale + sign(x)/gamma as bf16. One block per row.
__global__ __launch_bounds__(256) void quant_a(
    const float* __restrict__ in, const float* __restrict__ gamma,
    uint16_t* __restrict__ aq, float* __restrict__ scale)
{
    const int row = blockIdx.x;
    const int tid = threadIdx.x;
    const float* rp = in + (size_t)row * K_IN + tid * 8;
    float4 x0 = ((const float4*)rp)[0];
    float4 x1 = ((const float4*)rp)[1];
    float4 g0 = ((const float4*)(gamma + tid * 8))[0];
    float4 g1 = ((const float4*)(gamma + tid * 8))[1];
    float xs[8] = {x0.x, x0.y, x0.z, x0.w, x1.x, x1.y, x1.z, x1.w};
    float gs[8] = {g0.x, g0.y, g0.z, g0.w, g1.x, g1.y, g1.z, g1.w};

    float m = 0.f;
    uint16_t q[8];
    #pragma unroll
    for (int j = 0; j < 8; j++) {
        m = fmaxf(m, fabsf(xs[j]));
        float s = (xs[j] > 0.f) ? 1.f : ((xs[j] < 0.f) ? -1.f : 0.f);
        q[j] = f32_to_bf16_bits(s / gs[j]);
    }
    uint4 pk;
    pk.x = q[0] | ((uint32_t)q[1] << 16);
    pk.y = q[2] | ((uint32_t)q[3] << 16);
    pk.z = q[4] | ((uint32_t)q[5] << 16);
    pk.w = q[6] | ((uint32_t)q[7] << 16);
    *((uint4*)(aq + (size_t)row * K_IN + tid * 8)) = pk;

    #pragma unroll
    for (int off = 32; off > 0; off >>= 1) m = fmaxf(m, __shfl_down(m, off));
    __shared__ float sred[4];
    if ((tid & 63) == 0) sred[tid >> 6] = m;
    __syncthreads();
    if (tid == 0)
        scale[row] = fmaxf(fmaxf(sred[0], sred[1]), fmaxf(sred[2], sred[3]));
}

// ---------------------------------------------------------------------------
// Kernel 2: sign(w) as bf16 bits (+1 -> 0x3F80, -1 -> 0xBF80, 0 -> 0).
__global__ __launch_bounds__(256) void quant_w(
    const float* __restrict__ w, uint16_t* __restrict__ wq)
{
    const size_t base = ((size_t)blockIdx.x * 256 + threadIdx.x) * 8;
    float4 x0 = ((const float4*)(w + base))[0];
    float4 x1 = ((const float4*)(w + base))[1];
    float xs[8] = {x0.x, x0.y, x0.z, x0.w, x1.x, x1.y, x1.z, x1.w};
    uint16_t q[8];
    #pragma unroll
    for (int j = 0; j < 8; j++)
        q[j] = (xs[j] > 0.f) ? 0x3F80u : ((xs[j] < 0.f) ? 0xBF80u : 0u);
    uint4 pk;
    pk.x = q[0] | ((uint32_t)q[1] << 16);
    pk.y = q[2] | ((uint32_t)q[3] << 16);
    pk.z = q[4] | ((uint32_t)q[5] << 16);
    pk.w = q[6] | ((uint32_t)q[7] << 16);
    *((uint4*)(wq + base)) = pk;
}

// ---------------------------------------------------------------------------
// Kernel 3: bf16 MFMA GEMM, C[m,n] = sum_k Aq[m,k]*Wq[n,k] (both row-major,
// k contiguous). 128x128 block tile, BK=64, 4 waves each owning 64x64 via
// 4x4 grid of 16x16x32 MFMAs. m97-style staging via global_load_lds x16B.
#define BM 128
#define BN 128
#define BK 64

__global__ __launch_bounds__(256, 2) void gemm_q(
    const uint16_t* __restrict__ Aq,
    const uint16_t* __restrict__ Wq,
    const float* __restrict__ scale,
    const float* __restrict__ bias,
    const float* __restrict__ beta,
    float* __restrict__ out)
{
    __shared__ uint16_t As[BM * BK];   // 16 KB, no pad (global_load_lds constraint)
    __shared__ uint16_t Bs[BN * BK];   // 16 KB

    const int tid  = threadIdx.x;
    const int lane = tid & 63;
    const int wave = tid >> 6;

    const int row0 = blockIdx.x * BM;
    const int col0 = blockIdx.y * BN;

    const int wm = (wave >> 1) * 64;   // wave quadrant within 128x128
    const int wn = (wave & 1)  * 64;

    // staging: chunk c = i*256 + tid covers LDS row c>>3, cols (c&7)*8..+8
    const int st_row = tid >> 3;       // 0..31
    const int st_col = (tid & 7) * 8;

    const uint16_t* gA = Aq + (size_t)(row0 + st_row) * K_IN + st_col;
    const uint16_t* gB = Wq + (size_t)(col0 + st_row) * K_IN + st_col;
    uint16_t* lA = &As[st_row * BK + st_col];
    uint16_t* lB = &Bs[st_row * BK + st_col];

    f32x4 acc[4][4];
    #pragma unroll
    for (int i = 0; i < 4; i++) {
        #pragma unroll
        for (int j = 0; j < 4; j++) acc[i][j] = (f32x4)(0.f);
    }

    const int fr = lane & 15;          // fragment row (m or n)
    const int fk = (lane >> 4) * 8;    // fragment k offset

    for (int k0 = 0; k0 < K_IN; k0 += BK) {
        #pragma unroll
        for (int i = 0; i < 4; i++)
            load_lds16(gA + (size_t)(i * 32) * K_IN + k0, lA + i * 32 * BK);
        #pragma unroll
        for (int i = 0; i < 4; i++)
            load_lds16(gB + (size_t)(i * 32) * K_IN + k0, lB + i * 32 * BK);
        __syncthreads();   // compiler emits vmcnt(0) drain for the lds-DMA

        #pragma unroll
        for (int kk = 0; kk < BK; kk += 32) {
            bf16x8 a[4], b[4];
            #pragma unroll
            for (int mi = 0; mi < 4; mi++)
                a[mi] = *(const bf16x8*)&As[(wm + mi * 16 + fr) * BK + kk + fk];
            #pragma unroll
            for (int ni = 0; ni < 4; ni++)
                b[ni] = *(const bf16x8*)&Bs[(wn + ni * 16 + fr) * BK + kk + fk];
            #pragma unroll
            for (int mi = 0; mi < 4; mi++) {
                #pragma unroll
                for (int ni = 0; ni < 4; ni++)
                    acc[mi][ni] = __builtin_amdgcn_mfma_f32_16x16x32_bf16(
                        a[mi], b[ni], acc[mi][ni], 0, 0, 0);
            }
        }
        __syncthreads();
    }

    // epilogue: C/D layout col=lane&15, row=(lane>>4)*4+reg
    const int ecol = lane & 15;
    const int erow = (lane >> 4) * 4;

    float bi[4], be[4];
    #pragma unroll
    for (int ni = 0; ni < 4; ni++) {
        int col = col0 + wn + ni * 16 + ecol;
        bi[ni] = bias[col];
        be[ni] = beta[col];
    }
    #pragma unroll
    for (int mi = 0; mi < 4; mi++) {
        int rbase = row0 + wm + mi * 16 + erow;
        float sc[4];
        #pragma unroll
        for (int r = 0; r < 4; r++) sc[r] = scale[rbase + r];
        #pragma unroll
        for (int ni = 0; ni < 4; ni++) {
            int col = col0 + wn + ni * 16 + ecol;
            float* op = out + (size_t)rbase * N_OUT + col;
            #pragma unroll
            for (int r = 0; r < 4; r++)
                op[(size_t)r * N_OUT] = (acc[mi][ni][r] * sc[r] + bi[ni]) * be[ni];
        }
    }
}

// ---------------------------------------------------------------------------
// Fallback (no workspace needed): correct but slow. One block per input row.
__global__ __launch_bounds__(256) void fallback_kernel(
    const float* __restrict__ in, const float* __restrict__ w,
    const float* __restrict__ bias, const float* __restrict__ gamma,
    const float* __restrict__ beta, float* __restrict__ out)
{
    __shared__ float s_sign[K_IN];  // sign(x)/gamma
    __shared__ float sred[4];
    const int row = blockIdx.x;
    const int tid = threadIdx.x;
    float m = 0.f;
    for (int k = tid; k < K_IN; k += 256) {
        float x = in[(size_t)row * K_IN + k];
        m = fmaxf(m, fabsf(x));
        float s = (x > 0.f) ? 1.f : ((x < 0.f) ? -1.f : 0.f);
        s_sign[k] = s / gamma[k];
    }
    #pragma unroll
    for (int off = 32; off > 0; off >>= 1) m = fmaxf(m, __shfl_down(m, off));
    if ((tid & 63) == 0) sred[tid >> 6] = m;
    __syncthreads();
    float qs = fmaxf(fmaxf(sred[0], sred[1]), fmaxf(sred[2], sred[3]));
    for (int o = tid; o < N_OUT; o += 256) {
        const float* wr = w + (size_t)o * K_IN;
        float acc2 = 0.f;
        for (int k = 0; k < K_IN; k++) {
            float wv = wr[k];
            float ws_ = (wv > 0.f) ? 1.f : ((wv < 0.f) ? -1.f : 0.f);
            acc2 += s_sign[k] * ws_;
        }
        out[(size_t)row * N_OUT + o] = (acc2 * qs + bias[o]) * beta[o];
    }
}

// ---------------------------------------------------------------------------
extern "C" void kernel_launch(void* const* d_in, const int* in_sizes, int n_in,
                              void* d_out, int out_size, void* d_ws, size_t ws_size,
                              hipStream_t stream) {
    const float* input  = (const float*)d_in[0];
    const float* weight = (const float*)d_in[1];
    const float* bias   = (const float*)d_in[2];
    const float* gamma  = (const float*)d_in[3];
    const float* beta   = (const float*)d_in[4];
    float* out = (float*)d_out;

    const size_t aq_bytes = (size_t)M_ROWS * K_IN * sizeof(uint16_t);  // 32 MB
    const size_t wq_bytes = (size_t)N_OUT * K_IN * sizeof(uint16_t);   //  8 MB
    const size_t sc_bytes = (size_t)M_ROWS * sizeof(float);            // 32 KB

    if (ws_size >= aq_bytes + wq_bytes + sc_bytes) {
        uint16_t* aq    = (uint16_t*)d_ws;
        uint16_t* wq    = (uint16_t*)((char*)d_ws + aq_bytes);
        float*    scale = (float*)((char*)d_ws + aq_bytes + wq_bytes);

        quant_a<<<M_ROWS, 256, 0, stream>>>(input, gamma, aq, scale);
        quant_w<<<(N_OUT * K_IN) / (256 * 8), 256, 0, stream>>>(weight, wq);
        dim3 grid(M_ROWS / BM, N_OUT / BN);
        gemm_q<<<grid, 256, 0, stream>>>(aq, wq, scale, bias, beta, out);
    } else {
        fallback_kernel<<<M_ROWS, 256, 0, stream>>>(input, weight, bias, gamma, beta, out);
    }
}

// Round 2
// 163.348 us; speedup vs baseline: 1.2708x; 1.2708x over previous
//
#include <hip/hip_runtime.h>
#include <hip/hip_bf16.h>
#include <hip/hip_fp8.h>
#include <stdint.h>

#define M_ROWS 8192
#define K_IN   2048
#define N_OUT  2048

typedef int   v4i   __attribute__((ext_vector_type(4)));
typedef int   v8i   __attribute__((ext_vector_type(8)));
typedef float f32x4 __attribute__((ext_vector_type(4)));

// ---------------------------------------------------------------------------
// async global->LDS, 16B per lane. LDS dest = wave-uniform base + lane*16.
__device__ __forceinline__ void load_lds16(const void* g, void* l) {
    __builtin_amdgcn_global_load_lds(
        (const __attribute__((address_space(1))) uint32_t*)g,
        (__attribute__((address_space(3))) uint32_t*)l,
        16, 0, 0);
}

// ---------------------------------------------------------------------------
// Fused quantization. Blocks [0, M_ROWS): per-row absmax + sign(x) as fp8
// (+1 -> 0x38, -1 -> 0xB8, 0 -> 0x00). Blocks [M_ROWS, M_ROWS+2048):
// weights, sign(w)/gamma[k] as fp8 e4m3.
__global__ __launch_bounds__(256) void quant_fused(
    const float* __restrict__ in, const float* __restrict__ w,
    const float* __restrict__ gamma,
    uint8_t* __restrict__ aq, uint8_t* __restrict__ wq,
    float* __restrict__ scale)
{
    __shared__ float sred[4];
    const int tid = threadIdx.x;
    if (blockIdx.x < M_ROWS) {
        const int row = blockIdx.x;
        const float* rp = in + (size_t)row * K_IN + tid * 8;
        float4 x0 = ((const float4*)rp)[0];
        float4 x1 = ((const float4*)rp)[1];
        float xs[8] = {x0.x, x0.y, x0.z, x0.w, x1.x, x1.y, x1.z, x1.w};
        float m = 0.f;
        uint32_t lo = 0, hi = 0;
        #pragma unroll
        for (int j = 0; j < 8; j++) {
            m = fmaxf(m, fabsf(xs[j]));
            uint32_t b = (xs[j] > 0.f) ? 0x38u : ((xs[j] < 0.f) ? 0xB8u : 0u);
            if (j < 4) lo |= b << (8 * j); else hi |= b << (8 * (j - 4));
        }
        uint2 pk; pk.x = lo; pk.y = hi;
        *((uint2*)(aq + (size_t)row * K_IN + tid * 8)) = pk;

        #pragma unroll
        for (int off = 32; off > 0; off >>= 1) m = fmaxf(m, __shfl_down(m, off));
        if ((tid & 63) == 0) sred[tid >> 6] = m;
        __syncthreads();
        if (tid == 0)
            scale[row] = fmaxf(fmaxf(sred[0], sred[1]), fmaxf(sred[2], sred[3]));
    } else {
        const int wb = blockIdx.x - M_ROWS;
        const size_t base = ((size_t)wb * 256 + tid) * 8;
        const int k = (int)(base & (K_IN - 1));
        float4 x0 = ((const float4*)(w + base))[0];
        float4 x1 = ((const float4*)(w + base))[1];
        float4 g0 = ((const float4*)(gamma + k))[0];
        float4 g1 = ((const float4*)(gamma + k))[1];
        float xs[8] = {x0.x, x0.y, x0.z, x0.w, x1.x, x1.y, x1.z, x1.w};
        float gs[8] = {g0.x, g0.y, g0.z, g0.w, g1.x, g1.y, g1.z, g1.w};
        uint32_t lo = 0, hi = 0;
        #pragma unroll
        for (int j = 0; j < 8; j++) {
            float s = (xs[j] > 0.f) ? 1.f : ((xs[j] < 0.f) ? -1.f : 0.f);
            float v = s / gs[j];
            __hip_fp8_e4m3 f(v);
            uint32_t b = (uint32_t)f.__x;
            if (j < 4) lo |= b << (8 * j); else hi |= b << (8 * (j - 4));
        }
        uint2 pk; pk.x = lo; pk.y = hi;
        *((uint2*)(wq + base)) = pk;
    }
}

// ---------------------------------------------------------------------------
// MX-fp8 MFMA GEMM: C[m,n] = sum_k Aq[m,k]*Wq[n,k], both fp8 row-major
// (k contiguous). 128x128 block tile, BK=128 bytes, 4 waves each owning
// 64x64 via 4x4 grid of 16x16x128 scaled MFMAs with unit (0x7F) scales.
// LDS XOR swizzle: physical 16B chunk = logical chunk ^ (row & 7) — spreads
// fragment ds_read_b128 across all 32 banks (global source address is
// swizzled; LDS dest stays lane-contiguous for global_load_lds).
#define BM  128
#define BN  128
#define BKB 128

__global__ __launch_bounds__(256, 2) void gemm_q(
    const uint8_t* __restrict__ Aq,
    const uint8_t* __restrict__ Wq,
    const float* __restrict__ scale,
    const float* __restrict__ bias,
    const float* __restrict__ beta,
    float* __restrict__ out)
{
    __shared__ uint8_t As[BM * BKB];   // 16 KB
    __shared__ uint8_t Bs[BN * BKB];   // 16 KB

    const int tid  = threadIdx.x;
    const int lane = tid & 63;
    const int wave = tid >> 6;

    const int row0 = blockIdx.x * BM;
    const int col0 = blockIdx.y * BN;

    const int wm = (wave >> 1) * 64;
    const int wn = (wave & 1)  * 64;

    // staging: thread t (issue i) covers LDS row i*32 + (t>>3), phys chunk t&7
    const int st_row = tid >> 3;                 // 0..31
    const int st_pc  = tid & 7;                  // physical 16B chunk
    const int st_gc  = st_pc ^ (st_row & 7);     // swizzled source chunk

    const uint8_t* gA = Aq + (size_t)(row0 + st_row) * K_IN + st_gc * 16;
    const uint8_t* gB = Wq + (size_t)(col0 + st_row) * K_IN + st_gc * 16;
    uint8_t* lA = &As[st_row * BKB + st_pc * 16];
    uint8_t* lB = &Bs[st_row * BKB + st_pc * 16];

    f32x4 acc[4][4];
    #pragma unroll
    for (int i = 0; i < 4; i++) {
        #pragma unroll
        for (int j = 0; j < 4; j++) acc[i][j] = (f32x4)(0.f);
    }

    const int fr = lane & 15;            // fragment row (m or n)
    const int g2 = (lane >> 4) * 2;      // first logical chunk of this k-group
    const int off0 = ((g2     ^ (fr & 7)) << 4);
    const int off1 = (((g2+1) ^ (fr & 7)) << 4);

    for (int k0 = 0; k0 < K_IN; k0 += BKB) {
        #pragma unroll
        for (int i = 0; i < 4; i++)
            load_lds16(gA + (size_t)(i * 32) * K_IN + k0, lA + i * 32 * BKB);
        #pragma unroll
        for (int i = 0; i < 4; i++)
            load_lds16(gB + (size_t)(i * 32) * K_IN + k0, lB + i * 32 * BKB);
        __syncthreads();

        v8i a[4], b[4];
        #pragma unroll
        for (int mi = 0; mi < 4; mi++) {
            const uint8_t* p = &As[(wm + mi * 16 + fr) * BKB];
            v4i lo = *(const v4i*)(p + off0);
            v4i hi = *(const v4i*)(p + off1);
            a[mi] = (v8i){lo.x, lo.y, lo.z, lo.w, hi.x, hi.y, hi.z, hi.w};
        }
        #pragma unroll
        for (int ni = 0; ni < 4; ni++) {
            const uint8_t* p = &Bs[(wn + ni * 16 + fr) * BKB];
            v4i lo = *(const v4i*)(p + off0);
            v4i hi = *(const v4i*)(p + off1);
            b[ni] = (v8i){lo.x, lo.y, lo.z, lo.w, hi.x, hi.y, hi.z, hi.w};
        }
        #pragma unroll
        for (int mi = 0; mi < 4; mi++) {
            #pragma unroll
            for (int ni = 0; ni < 4; ni++)
                acc[mi][ni] = __builtin_amdgcn_mfma_scale_f32_16x16x128_f8f6f4(
                    a[mi], b[ni], acc[mi][ni],
                    0 /*cbsz: A=fp8*/, 0 /*blgp: B=fp8*/,
                    0, 0x7F7F7F7F,   /* A scales = 1.0 */
                    0, 0x7F7F7F7F);  /* B scales = 1.0 */
        }
        __syncthreads();
    }

    // epilogue: C/D layout col=lane&15, row=(lane>>4)*4+reg
    const int ecol = lane & 15;
    const int erow = (lane >> 4) * 4;

    float bi[4], be[4];
    #pragma unroll
    for (int ni = 0; ni < 4; ni++) {
        int col = col0 + wn + ni * 16 + ecol;
        bi[ni] = bias[col];
        be[ni] = beta[col];
    }
    #pragma unroll
    for (int mi = 0; mi < 4; mi++) {
        int rbase = row0 + wm + mi * 16 + erow;
        float sc[4];
        #pragma unroll
        for (int r = 0; r < 4; r++) sc[r] = scale[rbase + r];
        #pragma unroll
        for (int ni = 0; ni < 4; ni++) {
            int col = col0 + wn + ni * 16 + ecol;
            float* op = out + (size_t)rbase * N_OUT + col;
            #pragma unroll
            for (int r = 0; r < 4; r++)
                op[(size_t)r * N_OUT] = (acc[mi][ni][r] * sc[r] + bi[ni]) * be[ni];
        }
    }
}

// ---------------------------------------------------------------------------
// Fallback (no workspace): correct but slow.
__global__ __launch_bounds__(256) void fallback_kernel(
    const float* __restrict__ in, const float* __restrict__ w,
    const float* __restrict__ bias, const float* __restrict__ gamma,
    const float* __restrict__ beta, float* __restrict__ out)
{
    __shared__ float s_sign[K_IN];
    __shared__ float sred[4];
    const int row = blockIdx.x;
    const int tid = threadIdx.x;
    float m = 0.f;
    for (int k = tid; k < K_IN; k += 256) {
        float x = in[(size_t)row * K_IN + k];
        m = fmaxf(m, fabsf(x));
        float s = (x > 0.f) ? 1.f : ((x < 0.f) ? -1.f : 0.f);
        s_sign[k] = s / gamma[k];
    }
    #pragma unroll
    for (int off = 32; off > 0; off >>= 1) m = fmaxf(m, __shfl_down(m, off));
    if ((tid & 63) == 0) sred[tid >> 6] = m;
    __syncthreads();
    float qs = fmaxf(fmaxf(sred[0], sred[1]), fmaxf(sred[2], sred[3]));
    for (int o = tid; o < N_OUT; o += 256) {
        const float* wr = w + (size_t)o * K_IN;
        float acc2 = 0.f;
        for (int k = 0; k < K_IN; k++) {
            float wv = wr[k];
            float ws_ = (wv > 0.f) ? 1.f : ((wv < 0.f) ? -1.f : 0.f);
            acc2 += s_sign[k] * ws_;
        }
        out[(size_t)row * N_OUT + o] = (acc2 * qs + bias[o]) * beta[o];
    }
}

// ---------------------------------------------------------------------------
extern "C" void kernel_launch(void* const* d_in, const int* in_sizes, int n_in,
                              void* d_out, int out_size, void* d_ws, size_t ws_size,
                              hipStream_t stream) {
    const float* input  = (const float*)d_in[0];
    const float* weight = (const float*)d_in[1];
    const float* bias   = (const float*)d_in[2];
    const float* gamma  = (const float*)d_in[3];
    const float* beta   = (const float*)d_in[4];
    float* out = (float*)d_out;

    const size_t aq_bytes = (size_t)M_ROWS * K_IN;            // 16 MB
    const size_t wq_bytes = (size_t)N_OUT * K_IN;             //  4 MB
    const size_t sc_bytes = (size_t)M_ROWS * sizeof(float);   // 32 KB

    if (ws_size >= aq_bytes + wq_bytes + sc_bytes) {
        uint8_t* aq    = (uint8_t*)d_ws;
        uint8_t* wq    = (uint8_t*)d_ws + aq_bytes;
        float*   scale = (float*)((char*)d_ws + aq_bytes + wq_bytes);

        const int wq_blocks = (N_OUT * K_IN) / (256 * 8);     // 2048
        quant_fused<<<M_ROWS + wq_blocks, 256, 0, stream>>>(
            input, weight, gamma, aq, wq, scale);
        dim3 grid(M_ROWS / BM, N_OUT / BN);
        gemm_q<<<grid, 256, 0, stream>>>(aq, wq, scale, bias, beta, out);
    } else {
        fallback_kernel<<<M_ROWS, 256, 0, stream>>>(input, weight, bias, gamma, beta, out);
    }
}